// Round 2
// baseline (5381.194 us; speedup 1.0000x reference)
//
#include <hip/hip_runtime.h>
#include <stdint.h>

#define BATCH 8
#define K 65536
#define CFEAT 128
#define NPROP 1024
#define M 16            // workgroups per batch
#define T 256           // threads per WG
#define PTS (K / M)     // 4096 points per WG
#define PPT (PTS / T)   // 16 points per thread
#define WPB (M * (T / 64))   // 64 waves (= exchange slots) per batch

// d_out layout (float32): new_xyz (B,N,3) | new_features (B,C,N) | inds (B,N) as float
#define OUT_FEAT (BATCH * NPROP * 3)                         // 24576
#define OUT_INDS (BATCH * NPROP * 3 + BATCH * CFEAT * NPROP) // 1073152

// ws layout: slot[2][BATCH][WPB] blocks, each padded to its OWN 64B cacheline
// (8 ulls). Within a block: [0]=key{dist|0xFFFF-g|tag}, [1]={tag<<32|z},
// [2]={tag<<32|x}, [3]={tag<<32|y}.
// ALL spin-path accesses are RELAXED agent-scope: every word self-validates
// via its embedded 16-bit iteration tag, so no acquire ordering is needed
// (acquire would emit buffer_inv and thrash L2 chip-wide). Exact tags +
// parity double-buffer make the barrier-free schedule safe: a wave writes
// its parity-p slot for round t+2 only after it finished polling round t+1,
// which requires every wave posted t+1, which requires every wave finished
// polling round t — so nobody still reads parity-p expecting tag t.
#define SLOT_STRIDE 8
#define WS_ULLS (2 * BATCH * WPB * SLOT_STRIDE)   // 8192 ulls = 64 KB

__global__ __launch_bounds__(256) void fps_init(unsigned long long* ws) {
    int i = blockIdx.x * 256 + threadIdx.x;
    if (i < WS_ULLS) ws[i] = 0ull;   // tag 0 never matches t in [1,1023]
}

// Wave-wide u32 max via DPP (VALU-latency chain, ~6 dependent steps instead
// of 6x ds_bpermute round-trips). Result is FULL max in lane 63 only.
// Values are all >= 0, so identity 0 is safe under either bound_ctrl
// semantics (old-preserve or zero-fill).
__device__ __forceinline__ unsigned int wave_umax63(unsigned int x) {
    int v = (int)x;
    int t;
    t = __builtin_amdgcn_update_dpp(v, v, 0x111, 0xF, 0xF, false);  // row_shr:1
    v = ((unsigned)t > (unsigned)v) ? t : v;
    t = __builtin_amdgcn_update_dpp(v, v, 0x112, 0xF, 0xF, false);  // row_shr:2
    v = ((unsigned)t > (unsigned)v) ? t : v;
    t = __builtin_amdgcn_update_dpp(v, v, 0x114, 0xF, 0xF, false);  // row_shr:4
    v = ((unsigned)t > (unsigned)v) ? t : v;
    t = __builtin_amdgcn_update_dpp(v, v, 0x118, 0xF, 0xF, false);  // row_shr:8
    v = ((unsigned)t > (unsigned)v) ? t : v;
    t = __builtin_amdgcn_update_dpp(v, v, 0x142, 0xF, 0xF, false);  // row_bcast:15
    v = ((unsigned)t > (unsigned)v) ? t : v;
    t = __builtin_amdgcn_update_dpp(v, v, 0x143, 0xF, 0xF, false);  // row_bcast:31
    v = ((unsigned)t > (unsigned)v) ? t : v;
    return (unsigned int)v;   // lane 63 holds max over all 64 lanes
}

__global__ __launch_bounds__(T) void fps_kernel(const float* __restrict__ xyz,
                                                float* __restrict__ out,
                                                unsigned long long* __restrict__ ws) {
    const int b = blockIdx.x & 7;   // batch's 16 WGs round-robin onto one XCD
    const int w = blockIdx.x >> 3;
    const int tid = threadIdx.x;
    const int lane = tid & 63;
    const int wv = tid >> 6;
    const float* xb = xyz + (size_t)b * (K * 3);
    const int base = w * PTS;

    __shared__ float sx[PTS], sy[PTS], sz[PTS];   // 48 KB: winner-coord recovery

    float px[PPT], py[PPT], pz[PPT], dist[PPT];
#pragma unroll
    for (int j = 0; j < PPT; ++j) {
        int l = j * T + tid;
        int g = base + l;
        px[j] = xb[3 * g];
        py[j] = xb[3 * g + 1];
        pz[j] = xb[3 * g + 2];
        sx[l] = px[j]; sy[l] = py[j]; sz[l] = pz[j];
        dist[j] = 1e10f;
    }
    float qx = xb[0], qy = xb[1], qz = xb[2];
    if (w == 0 && tid == 0) out[OUT_INDS + b * NPROP] = 0.0f;
    __syncthreads();   // sx/sy/sz visible to all waves; ONLY barrier in kernel

    for (int t = 1; t < NPROP; ++t) {
        // ---- local distance update + per-lane argmax (bit-exact vs numpy:
        // no FMA contraction, (dx2+dy2)+dz2 order, first-max tie-break via
        // strict > over ascending l) ----
        float bestd = -1.0f;
        unsigned int bestl = 0;
#pragma unroll
        for (int j = 0; j < PPT; ++j) {
            float dx = __fsub_rn(px[j], qx);
            float dy = __fsub_rn(py[j], qy);
            float dz = __fsub_rn(pz[j], qz);
            float d = __fadd_rn(__fadd_rn(__fmul_rn(dx, dx), __fmul_rn(dy, dy)),
                                __fmul_rn(dz, dz));
            float nd = fminf(dist[j], d);
            dist[j] = nd;
            unsigned int l = (unsigned int)(j * T + tid);
            bool gt = nd > bestd;
            bestd = gt ? nd : bestd;
            bestl = gt ? l : bestl;
        }
        // ---- wave-level two-phase argmax via DPP (dist >= 0 so float order
        // == u32 bit order; phase2 max(~l) == first-max tie-break) ----
        unsigned int du = __float_as_uint(bestd);
        unsigned int m1 = wave_umax63(du);
        unsigned int maxd = (unsigned int)__builtin_amdgcn_readlane((int)m1, 63);
        unsigned int cand = (du == maxd) ? ~bestl : 0u;
        unsigned int m2 = wave_umax63(cand);

        const int par = t & 1;
        unsigned long long* sgrp = ws + (size_t)((par * BATCH + b) * WPB) * SLOT_STRIDE;
        const unsigned int tt = (unsigned int)t;

        // ---- post this wave's winner immediately (no S1, no cross-wave scan) ----
        if (lane == 63) {
            unsigned int l = ~m2;                 // wave-winner local index
            float bx = sx[l], by = sy[l], bz = sz[l];
            unsigned int g = (unsigned int)base + l;
            unsigned long long* sme = sgrp + (size_t)(w * 4 + wv) * SLOT_STRIDE;
            unsigned long long tagHi = ((unsigned long long)tt) << 32;
            __hip_atomic_store(&sme[1], tagHi | __float_as_uint(bz),
                               __ATOMIC_RELAXED, __HIP_MEMORY_SCOPE_AGENT);
            __hip_atomic_store(&sme[2], tagHi | __float_as_uint(bx),
                               __ATOMIC_RELAXED, __HIP_MEMORY_SCOPE_AGENT);
            __hip_atomic_store(&sme[3], tagHi | __float_as_uint(by),
                               __ATOMIC_RELAXED, __HIP_MEMORY_SCOPE_AGENT);
            unsigned long long ka = ((unsigned long long)maxd << 32) |
                                    ((unsigned long long)(0xFFFFu - g) << 16) |
                                    (unsigned long long)tt;
            __hip_atomic_store(&sme[0], ka, __ATOMIC_RELAXED, __HIP_MEMORY_SCOPE_AGENT);
        }

        // ---- every wave polls all 64 slots itself (lane i <-> slot i); key
        // and payload load in the SAME poll round; all relaxed, self-tagged ----
        unsigned long long* sp = sgrp + (size_t)lane * SLOT_STRIDE;
        unsigned long long k, zt, xt, yt;
        for (;;) {
            k  = __hip_atomic_load(&sp[0], __ATOMIC_RELAXED, __HIP_MEMORY_SCOPE_AGENT);
            zt = __hip_atomic_load(&sp[1], __ATOMIC_RELAXED, __HIP_MEMORY_SCOPE_AGENT);
            xt = __hip_atomic_load(&sp[2], __ATOMIC_RELAXED, __HIP_MEMORY_SCOPE_AGENT);
            yt = __hip_atomic_load(&sp[3], __ATOMIC_RELAXED, __HIP_MEMORY_SCOPE_AGENT);
            if ((unsigned short)k == (unsigned short)tt) break;
        }
        // ---- global two-phase argmax over the 64 keys, again via DPP ----
        unsigned int hi = (unsigned int)(k >> 32);
        unsigned int lo = (unsigned int)k;
        unsigned int p1 = wave_umax63(hi);
        unsigned int maxk = (unsigned int)__builtin_amdgcn_readlane((int)p1, 63);
        unsigned int c2 = (hi == maxk) ? lo : 0u;   // lo = (0xFFFF-g)<<16 | t
        unsigned int p2 = wave_umax63(c2);
        unsigned int lw = (unsigned int)__builtin_amdgcn_readlane((int)p2, 63);
        unsigned int g = 0xFFFFu - (lw >> 16);
        int s = (int)((g >> 12) * 4 + ((g >> 6) & 3));   // winner slot (= wave)
        int addr = s << 2;
        // pull winner payload from the lane that polled slot s
        unsigned int zlo = (unsigned int)__builtin_amdgcn_ds_bpermute(addr, (int)(unsigned int)zt);
        unsigned int zhi = (unsigned int)__builtin_amdgcn_ds_bpermute(addr, (int)(unsigned int)(zt >> 32));
        unsigned int xlo = (unsigned int)__builtin_amdgcn_ds_bpermute(addr, (int)(unsigned int)xt);
        unsigned int xhi = (unsigned int)__builtin_amdgcn_ds_bpermute(addr, (int)(unsigned int)(xt >> 32));
        unsigned int ylo = (unsigned int)__builtin_amdgcn_ds_bpermute(addr, (int)(unsigned int)yt);
        unsigned int yhi = (unsigned int)__builtin_amdgcn_ds_bpermute(addr, (int)(unsigned int)(yt >> 32));
        if (zhi != tt || xhi != tt || yhi != tt) {
            // rare path: payload landed after key — relaxed re-read, each word
            // self-validates via its tag (uniform branch: bpermuted values
            // are wave-uniform)
            unsigned long long* sw = sgrp + (size_t)s * SLOT_STRIDE;
            unsigned long long zq, xq, yq;
            do { zq = __hip_atomic_load(&sw[1], __ATOMIC_RELAXED, __HIP_MEMORY_SCOPE_AGENT);
            } while ((unsigned int)(zq >> 32) != tt);
            do { xq = __hip_atomic_load(&sw[2], __ATOMIC_RELAXED, __HIP_MEMORY_SCOPE_AGENT);
            } while ((unsigned int)(xq >> 32) != tt);
            do { yq = __hip_atomic_load(&sw[3], __ATOMIC_RELAXED, __HIP_MEMORY_SCOPE_AGENT);
            } while ((unsigned int)(yq >> 32) != tt);
            zlo = (unsigned int)zq; xlo = (unsigned int)xq; ylo = (unsigned int)yq;
        }
        qx = __uint_as_float(xlo);
        qy = __uint_as_float(ylo);
        qz = __uint_as_float(zlo);
        if (w == 0 && tid == 0) out[OUT_INDS + b * NPROP + t] = (float)g;
    }
}

__global__ __launch_bounds__(256) void gather_kernel(const float* __restrict__ xyz,
                                                     const float* __restrict__ feat,
                                                     float* __restrict__ out) {
    int gid = blockIdx.x * 256 + threadIdx.x;   // covers B*C*N = 1,048,576
    int n = gid & (NPROP - 1);
    int b = gid >> 17;                          // C*N = 2^17
    int c = (gid >> 10) & (CFEAT - 1);
    int ind = (int)out[OUT_INDS + (b << 10) + n];   // float inds, exact < 2^24
    out[OUT_FEAT + gid] = feat[(((size_t)b * CFEAT + c) << 16) + (size_t)ind];
    if (gid < BATCH * NPROP) {
        int b2 = gid >> 10;
        int ind2 = (int)out[OUT_INDS + gid];
        const float* s = xyz + ((size_t)b2 * K + (size_t)ind2) * 3;
        float a0 = s[0], a1 = s[1], a2 = s[2];
        out[gid * 3 + 0] = a0;
        out[gid * 3 + 1] = a1;
        out[gid * 3 + 2] = a2;
    }
}

extern "C" void kernel_launch(void* const* d_in, const int* in_sizes, int n_in,
                              void* d_out, int out_size, void* d_ws, size_t ws_size,
                              hipStream_t stream) {
    const float* xyz = (const float*)d_in[0];
    const float* feat = (const float*)d_in[1];
    float* out = (float*)d_out;
    unsigned long long* ws = (unsigned long long*)d_ws;

    hipLaunchKernelGGL(fps_init, dim3(WS_ULLS / 256), dim3(256), 0, stream, ws);
    hipLaunchKernelGGL(fps_kernel, dim3(BATCH * M), dim3(T), 0, stream,
                       xyz, out, ws);
    hipLaunchKernelGGL(gather_kernel, dim3(BATCH * CFEAT * NPROP / 256), dim3(256),
                       0, stream, xyz, feat, out);
}

// Round 3
// 1972.118 us; speedup vs baseline: 2.7286x; 2.7286x over previous
//
#include <hip/hip_runtime.h>
#include <stdint.h>

#define BATCH 8
#define K 65536
#define CFEAT 128
#define NPROP 1024
#define M 16            // workgroups per batch
#define T 256           // threads per WG
#define PTS (K / M)     // 4096 points per WG
#define PPT (PTS / T)   // 16 points per thread

// d_out layout (float32): new_xyz (B,N,3) | new_features (B,C,N) | inds (B,N) as float
#define OUT_FEAT (BATCH * NPROP * 3)                         // 24576
#define OUT_INDS (BATCH * NPROP * 3 + BATCH * CFEAT * NPROP) // 1073152

// ws layout: slot[2][BATCH][M] lines, each padded to its OWN 64B cacheline.
// KEY-ONLY protocol: word [0] = key { dist_u32 | (0xFFFF-g)<<16 | tag }.
// Winner COORDS are never exchanged — they are re-fetched from the immutable
// xyz input via normal cached loads after the winner index is known.
// All spin-path accesses are RELAXED agent-scope (acquire would emit
// buffer_inv and thrash L2 chip-wide; round-2 experiment confirmed fabric
// traffic on this path is the dominant cost). The 16-bit exact tag +
// parity double-buffer make overwrite races impossible: a WG posts round t
// only after finishing its poll of round t-1, which requires every WG posted
// t-1, which requires every WG finished polling t-2 (the same-parity round).
#define SLOT_STRIDE 8
#define WS_ULLS (2 * BATCH * M * SLOT_STRIDE)   // 2048 ulls = 16 KB

__global__ __launch_bounds__(256) void fps_init(unsigned long long* ws) {
    int i = blockIdx.x * 256 + threadIdx.x;
    if (i < WS_ULLS) ws[i] = 0ull;   // tag 0 never matches t in [1,1023]
}

// Wave-wide u32 max via DPP (VALU-latency chain; HW-validated in round 2).
// Full 64-lane max lands in lane 63. Values >= 0 so self-identity is safe.
__device__ __forceinline__ unsigned int wave_umax63(unsigned int x) {
    int v = (int)x;
    int t;
    t = __builtin_amdgcn_update_dpp(v, v, 0x111, 0xF, 0xF, false);  // row_shr:1
    v = ((unsigned)t > (unsigned)v) ? t : v;
    t = __builtin_amdgcn_update_dpp(v, v, 0x112, 0xF, 0xF, false);  // row_shr:2
    v = ((unsigned)t > (unsigned)v) ? t : v;
    t = __builtin_amdgcn_update_dpp(v, v, 0x114, 0xF, 0xF, false);  // row_shr:4
    v = ((unsigned)t > (unsigned)v) ? t : v;
    t = __builtin_amdgcn_update_dpp(v, v, 0x118, 0xF, 0xF, false);  // row_shr:8
    v = ((unsigned)t > (unsigned)v) ? t : v;
    t = __builtin_amdgcn_update_dpp(v, v, 0x142, 0xF, 0xF, false);  // row_bcast:15
    v = ((unsigned)t > (unsigned)v) ? t : v;
    t = __builtin_amdgcn_update_dpp(v, v, 0x143, 0xF, 0xF, false);  // row_bcast:31
    v = ((unsigned)t > (unsigned)v) ? t : v;
    return (unsigned int)v;
}

// 16-lane (row 0) u32 max via DPP; max of lanes 0..15 lands in lane 15.
__device__ __forceinline__ unsigned int row16_umax15(unsigned int x) {
    int v = (int)x;
    int t;
    t = __builtin_amdgcn_update_dpp(v, v, 0x111, 0xF, 0xF, false);  // row_shr:1
    v = ((unsigned)t > (unsigned)v) ? t : v;
    t = __builtin_amdgcn_update_dpp(v, v, 0x112, 0xF, 0xF, false);  // row_shr:2
    v = ((unsigned)t > (unsigned)v) ? t : v;
    t = __builtin_amdgcn_update_dpp(v, v, 0x114, 0xF, 0xF, false);  // row_shr:4
    v = ((unsigned)t > (unsigned)v) ? t : v;
    t = __builtin_amdgcn_update_dpp(v, v, 0x118, 0xF, 0xF, false);  // row_shr:8
    v = ((unsigned)t > (unsigned)v) ? t : v;
    return (unsigned int)v;
}

__global__ __launch_bounds__(T) void fps_kernel(const float* __restrict__ xyz,
                                                float* __restrict__ out,
                                                unsigned long long* __restrict__ ws) {
    const int b = blockIdx.x & 7;   // batch's 16 WGs round-robin onto one XCD
    const int w = blockIdx.x >> 3;
    const int tid = threadIdx.x;
    const int lane = tid & 63;
    const int wv = tid >> 6;
    const float* xb = xyz + (size_t)b * (K * 3);
    const int base = w * PTS;

    __shared__ unsigned long long s_wkey[T / 64];
    __shared__ int s_g;

    float px[PPT], py[PPT], pz[PPT], dist[PPT];
#pragma unroll
    for (int j = 0; j < PPT; ++j) {
        int l = j * T + tid;
        int g = base + l;
        px[j] = xb[3 * g];
        py[j] = xb[3 * g + 1];
        pz[j] = xb[3 * g + 2];
        dist[j] = 1e10f;
    }
    float qx = xb[0], qy = xb[1], qz = xb[2];
    if (w == 0 && tid == 0) out[OUT_INDS + b * NPROP] = 0.0f;

    for (int t = 1; t < NPROP; ++t) {
        // ---- local distance update + per-lane argmax (bit-exact vs numpy:
        // no FMA contraction, (dx2+dy2)+dz2 order, first-max tie-break via
        // strict > over ascending l) ----
        float bestd = -1.0f;
        unsigned int bestl = 0;
#pragma unroll
        for (int j = 0; j < PPT; ++j) {
            float dx = __fsub_rn(px[j], qx);
            float dy = __fsub_rn(py[j], qy);
            float dz = __fsub_rn(pz[j], qz);
            float d = __fadd_rn(__fadd_rn(__fmul_rn(dx, dx), __fmul_rn(dy, dy)),
                                __fmul_rn(dz, dz));
            float nd = fminf(dist[j], d);
            dist[j] = nd;
            unsigned int l = (unsigned int)(j * T + tid);
            bool gt = nd > bestd;
            bestd = gt ? nd : bestd;
            bestl = gt ? l : bestl;
        }
        // ---- wave-level two-phase argmax via DPP (dist >= 0 so float order
        // == u32 bit order; phase2 max(~l) == first-max tie-break) ----
        unsigned int du = __float_as_uint(bestd);
        unsigned int m1 = wave_umax63(du);
        unsigned int maxd = (unsigned int)__builtin_amdgcn_readlane((int)m1, 63);
        unsigned int cand = (du == maxd) ? ~bestl : 0u;
        unsigned int m2 = wave_umax63(cand);

        const int par = t & 1;
        unsigned long long* sgrp = ws + (size_t)((par * BATCH + b) * M) * SLOT_STRIDE;
        const unsigned int tt = (unsigned int)t;

        if (lane == 63) {
            unsigned int l = ~m2;                 // wave-winner local index
            unsigned int g = (unsigned int)base + l;
            s_wkey[wv] = ((unsigned long long)maxd << 32) |
                         ((unsigned long long)((0xFFFFu - g) & 0xFFFFu) << 16) |
                         (unsigned long long)tt;
        }
        __syncthreads();   // S1

        if (tid == 0) {
            // cross-wave max over 4 keys (u64 compare == lexicographic
            // (dist, 0xFFFF-g) since tag bits are equal)
            unsigned long long kb = s_wkey[0];
#pragma unroll
            for (int i = 1; i < T / 64; ++i) kb = (s_wkey[i] > kb) ? s_wkey[i] : kb;
            __hip_atomic_store(&sgrp[(size_t)w * SLOT_STRIDE], kb,
                               __ATOMIC_RELAXED, __HIP_MEMORY_SCOPE_AGENT);
        }

        // ---- spin-exchange: lanes 0..15 watch one padded key line each ----
        if (tid < M) {
            unsigned long long* sp = sgrp + (size_t)tid * SLOT_STRIDE;
            unsigned long long k;
            do {
                k = __hip_atomic_load(sp, __ATOMIC_RELAXED, __HIP_MEMORY_SCOPE_AGENT);
            } while ((unsigned short)k != (unsigned short)tt);
            // two-phase argmax over 16 keys via DPP (row 0 only is active)
            unsigned int hi = (unsigned int)(k >> 32);
            unsigned int lo = (unsigned int)k;
            unsigned int p1 = row16_umax15(hi);
            unsigned int maxk = (unsigned int)__builtin_amdgcn_readlane((int)p1, 15);
            unsigned int c2 = (hi == maxk) ? lo : 0u;   // lo = (0xFFFF-g)<<16 | t
            unsigned int p2 = row16_umax15(c2);
            unsigned int low = (unsigned int)__builtin_amdgcn_readlane((int)p2, 15);
            unsigned int g = 0xFFFFu - (low >> 16);
            if (tid == 0) {
                s_g = (int)g;
                if (w == 0) out[OUT_INDS + b * NPROP + t] = (float)g;
            }
        }
        __syncthreads();   // S2
        // winner coords re-fetched from immutable input (L1/L2-cached,
        // same-address broadcast across all lanes)
        int g = s_g;
        qx = xb[3 * g];
        qy = xb[3 * g + 1];
        qz = xb[3 * g + 2];
    }
}

__global__ __launch_bounds__(256) void gather_kernel(const float* __restrict__ xyz,
                                                     const float* __restrict__ feat,
                                                     float* __restrict__ out) {
    int gid = blockIdx.x * 256 + threadIdx.x;   // covers B*C*N = 1,048,576
    int n = gid & (NPROP - 1);
    int b = gid >> 17;                          // C*N = 2^17
    int c = (gid >> 10) & (CFEAT - 1);
    int ind = (int)out[OUT_INDS + (b << 10) + n];   // float inds, exact < 2^24
    out[OUT_FEAT + gid] = feat[(((size_t)b * CFEAT + c) << 16) + (size_t)ind];
    if (gid < BATCH * NPROP) {
        int b2 = gid >> 10;
        int ind2 = (int)out[OUT_INDS + gid];
        const float* s = xyz + ((size_t)b2 * K + (size_t)ind2) * 3;
        float a0 = s[0], a1 = s[1], a2 = s[2];
        out[gid * 3 + 0] = a0;
        out[gid * 3 + 1] = a1;
        out[gid * 3 + 2] = a2;
    }
}

extern "C" void kernel_launch(void* const* d_in, const int* in_sizes, int n_in,
                              void* d_out, int out_size, void* d_ws, size_t ws_size,
                              hipStream_t stream) {
    const float* xyz = (const float*)d_in[0];
    const float* feat = (const float*)d_in[1];
    float* out = (float*)d_out;
    unsigned long long* ws = (unsigned long long*)d_ws;

    hipLaunchKernelGGL(fps_init, dim3(WS_ULLS / 256), dim3(256), 0, stream, ws);
    hipLaunchKernelGGL(fps_kernel, dim3(BATCH * M), dim3(T), 0, stream,
                       xyz, out, ws);
    hipLaunchKernelGGL(gather_kernel, dim3(BATCH * CFEAT * NPROP / 256), dim3(256),
                       0, stream, xyz, feat, out);
}